// Round 13
// baseline (363.093 us; speedup 1.0000x reference)
//
#include <hip/hip_runtime.h>

#define N_NODES 10000
#define N_EDGES 640000
#define DD 128

typedef __attribute__((ext_vector_type(8))) short short8;
typedef __attribute__((ext_vector_type(8))) float f32x8;
typedef __attribute__((ext_vector_type(4))) float f32x4;
typedef __attribute__((ext_vector_type(2))) float f32x2;

// pack two fp32 -> (bf16(hi)<<16)|bf16(lo), truncating: one v_perm_b32
__device__ __forceinline__ unsigned pack_bf2(float lo, float hi) {
  return __builtin_amdgcn_perm(__float_as_uint(hi), __float_as_uint(lo), 0x07060302u);
}

// Stage W (128x128 fp32 row-major) into LDS as bf16 with per-row XOR swizzle
// on 16B chunks (256-thread): chunk c of row j at slot (j*16)|(c^(j&7)).
__device__ __forceinline__ void stage_w256(const float* __restrict__ W,
                                           short8* lwr) {
  const int tid = threadIdx.x;
#pragma unroll
  for (int t = 0; t < 8; ++t) {
    int s = t * 256 + tid;                          // chunk id 0..2047
    f32x8 v = *(const f32x8*)(W + (size_t)s * 8);   // coalesced 32B cached
    short8 av;
    unsigned* au = (unsigned*)&av;
    au[0] = pack_bf2(v[0], v[1]);
    au[1] = pack_bf2(v[2], v[3]);
    au[2] = pack_bf2(v[4], v[5]);
    au[3] = pack_bf2(v[6], v[7]);
    int j = s >> 4;
    int c = s & 15;
    lwr[(j << 4) | (c ^ (j & 7))] = av;
  }
  __syncthreads();
}

// ---------------------------------------------------------------------------
// k_zero: zero count histogram AND segY accumulator (atomically built now)
// ---------------------------------------------------------------------------
__global__ __launch_bounds__(256) void k_zero(int* __restrict__ count,
                                              float* __restrict__ segY) {
  const int i = blockIdx.x * 256 + threadIdx.x;
  if (i < N_NODES) count[i] = 0;
  if (i < N_NODES * DD) segY[i] = 0.f;
}

__global__ __launch_bounds__(256) void k_hist(const int* __restrict__ EI,
                                              int* __restrict__ count) {
  const int e = blockIdx.x * 256 + threadIdx.x;
  atomicAdd(&count[EI[2 * e]], 1);
}

__global__ __launch_bounds__(1024) void k_scan(const int* __restrict__ count,
                                               int* __restrict__ rowptr,
                                               int* __restrict__ cursor) {
  __shared__ int part[1024];
  const int tid = threadIdx.x;
  const int base = tid * 10;
  int local[10];
  int s = 0;
#pragma unroll
  for (int i = 0; i < 10; ++i) {
    const int idx = base + i;
    const int v = (idx < N_NODES) ? count[idx] : 0;
    local[i] = s;
    s += v;
  }
  part[tid] = s;
  __syncthreads();
  for (int off = 1; off < 1024; off <<= 1) {
    int v = 0;
    if (tid >= off) v = part[tid - off];
    __syncthreads();
    if (tid >= off) part[tid] += v;
    __syncthreads();
  }
  const int excl = (tid > 0) ? part[tid - 1] : 0;
#pragma unroll
  for (int i = 0; i < 10; ++i) {
    const int idx = base + i;
    if (idx < N_NODES) {
      const int r = excl + local[i];
      rowptr[idx] = r;
      cursor[idx] = r;
    }
  }
  if (tid == 1023) rowptr[N_NODES] = part[1023];
}

// k_fill: CSR fill + per-position node id (nid) for the fused segment-sum
__global__ __launch_bounds__(256) void k_fill(const int* __restrict__ EI,
                                              int* __restrict__ cursor,
                                              int* __restrict__ col,
                                              int* __restrict__ nid) {
  const int e = blockIdx.x * 256 + threadIdx.x;
  const int s = EI[2 * e];
  const int pos = atomicAdd(&cursor[s], 1);
  col[pos] = e;
  nid[pos] = s;
}

// ---------------------------------------------------------------------------
// k_mega: CSR-ORDERED gemm + fused segment-sum. Block b owns CSR positions
// [b*256, b*256+256).
//   Phase 2: 4 x (64-row permuted gemm tile): row e=col[p]; Yp[e] = W @ Y[e]
//     (swapped-operand MFMA -> contiguous dwordx4 NT stores, rows permuted).
//   Phase 3: per-wave segmented sum of 64 positions: rows are L1/L2-hot from
//     phase 2 (same block just loaded them); per-(node,block) partials flushed
//     with low-contention fp32 atomics (~2.5M dwords total).
// Y is read from HBM exactly once for BOTH outputs (no separate gather pass).
// ---------------------------------------------------------------------------
__global__ __launch_bounds__(256, 2) void k_mega(
    const float* __restrict__ Y,
    const float* __restrict__ W,
    const int* __restrict__ col,
    const int* __restrict__ nid,
    float* __restrict__ Yp,
    float* __restrict__ segY) {
  __shared__ short8 lwr[2048];   // 32 KB swizzled bf16 W
  stage_w256(W, lwr);
  const int wid  = threadIdx.x >> 6;
  const int lane = threadIdx.x & 63;
  const int l15  = lane & 15;
  const int lg   = lane >> 4;
  const int koff = lg * 8;
  const int base = blockIdx.x * 256;

  // ---------------- phase 2: 4 permuted gemm tiles ----------------
#pragma unroll 1
  for (int it = 0; it < 4; ++it) {
    const int p = base + it * 64 + wid * 16 + l15;
    const int e = col[p];
    const float* yr = Y + (size_t)e * DD;

    short8 a[4];
#pragma unroll
    for (int kk = 0; kk < 4; ++kk) {
      f32x8 v = *(const f32x8*)(yr + kk * 32 + koff);
      short8 av;
      unsigned* au = (unsigned*)&av;
      au[0] = pack_bf2(v[0], v[1]);
      au[1] = pack_bf2(v[2], v[3]);
      au[2] = pack_bf2(v[4], v[5]);
      au[3] = pack_bf2(v[6], v[7]);
      a[kk] = av;
    }

    f32x4 acc[8];
#pragma unroll
    for (int nt = 0; nt < 8; ++nt)
      acc[nt] = (f32x4){0.f, 0.f, 0.f, 0.f};

#pragma unroll
    for (int nt = 0; nt < 8; ++nt) {
      const int j = nt * 16 + l15;                  // W row (= output col blk)
#pragma unroll
      for (int kk = 0; kk < 4; ++kk) {
        const int kc = kk * 4 + lg;
        short8 b = lwr[(j << 4) | (kc ^ (j & 7))];
        acc[nt] = __builtin_amdgcn_mfma_f32_16x16x32_bf16(b, a[kk], acc[nt], 0, 0, 0);
      }
    }

    float* orow = Yp + (size_t)e * DD + lg * 4;
#pragma unroll
    for (int nt = 0; nt < 8; ++nt)
      __builtin_nontemporal_store(acc[nt], (f32x4*)(orow + nt * 16));
  }

  // ---------------- phase 3: segmented sum (wave window = 64 pos) --------
  const int q0 = base + wid * 64;
  const size_t co = 2 * (size_t)lane;
  f32x2 acc2 = (f32x2){0.f, 0.f};
  int cur = nid[q0];
  int j = 0;
#pragma unroll 1
  while (j < 64) {
    if (j + 8 <= 64 && nid[q0 + j + 7] == cur) {
      // fast path: 8 consecutive positions all in node `cur` (sandwiched by
      // non-decreasing nid) -> batched loads, full MLP
      const int p = q0 + j;
      f32x2 v0 = *(const f32x2*)(Y + (size_t)col[p]     * DD + co);
      f32x2 v1 = *(const f32x2*)(Y + (size_t)col[p + 1] * DD + co);
      f32x2 v2 = *(const f32x2*)(Y + (size_t)col[p + 2] * DD + co);
      f32x2 v3 = *(const f32x2*)(Y + (size_t)col[p + 3] * DD + co);
      f32x2 v4 = *(const f32x2*)(Y + (size_t)col[p + 4] * DD + co);
      f32x2 v5 = *(const f32x2*)(Y + (size_t)col[p + 5] * DD + co);
      f32x2 v6 = *(const f32x2*)(Y + (size_t)col[p + 6] * DD + co);
      f32x2 v7 = *(const f32x2*)(Y + (size_t)col[p + 7] * DD + co);
      acc2 += v0; acc2 += v1; acc2 += v2; acc2 += v3;
      acc2 += v4; acc2 += v5; acc2 += v6; acc2 += v7;
      j += 8;
    } else {
      const int n = nid[q0 + j];
      if (n != cur) {
        unsafeAtomicAdd(&segY[(size_t)cur * DD + co],     acc2[0]);
        unsafeAtomicAdd(&segY[(size_t)cur * DD + co + 1], acc2[1]);
        acc2 = (f32x2){0.f, 0.f};
        cur = n;
      }
      acc2 += *(const f32x2*)(Y + (size_t)col[q0 + j] * DD + co);
      ++j;
    }
  }
  unsafeAtomicAdd(&segY[(size_t)cur * DD + co],     acc2[0]);
  unsafeAtomicAdd(&segY[(size_t)cur * DD + co + 1], acc2[1]);
}

// ---------------------------------------------------------------------------
// Small GEMM + epilogue: X' = relu(X + segY @ W^T)  (10000x128, fp32 I/O)
// ---------------------------------------------------------------------------
__global__ __launch_bounds__(256, 2) void k_small(
    const float* __restrict__ segY,
    const float* __restrict__ W,
    const float* __restrict__ X,
    float* __restrict__ Xp) {
  __shared__ short8 lwr[2048];
  stage_w256(W, lwr);
  const int wid  = threadIdx.x >> 6;
  const int lane = threadIdx.x & 63;
  const int l15  = lane & 15;
  const int lg   = lane >> 4;
  const int koff = lg * 8;
  const int rbase = blockIdx.x * 128 + wid * 32;

  short8 a[2][4];
#pragma unroll
  for (int mt = 0; mt < 2; ++mt) {
    int row = rbase + mt * 16 + l15;
    if (row > N_NODES - 1) row = N_NODES - 1;   // clamp (stores guarded)
    const float* sr = segY + (size_t)row * DD + koff;
#pragma unroll
    for (int kk = 0; kk < 4; ++kk) {
      f32x8 v = *(const f32x8*)(sr + kk * 32);
      short8 av;
      unsigned* au = (unsigned*)&av;
      au[0] = pack_bf2(v[0], v[1]);
      au[1] = pack_bf2(v[2], v[3]);
      au[2] = pack_bf2(v[4], v[5]);
      au[3] = pack_bf2(v[6], v[7]);
      a[mt][kk] = av;
    }
  }

  f32x4 acc[2][8];
#pragma unroll
  for (int mt = 0; mt < 2; ++mt)
#pragma unroll
    for (int nt = 0; nt < 8; ++nt)
      acc[mt][nt] = (f32x4){0.f, 0.f, 0.f, 0.f};

#pragma unroll
  for (int nt = 0; nt < 8; ++nt) {
    const int j = nt * 16 + l15;
#pragma unroll
    for (int kk = 0; kk < 4; ++kk) {
      const int kc = kk * 4 + lg;
      short8 b = lwr[(j << 4) | (kc ^ (j & 7))];
      acc[0][nt] = __builtin_amdgcn_mfma_f32_16x16x32_bf16(b, a[0][kk], acc[0][nt], 0, 0, 0);
      acc[1][nt] = __builtin_amdgcn_mfma_f32_16x16x32_bf16(b, a[1][kk], acc[1][nt], 0, 0, 0);
    }
  }

#pragma unroll
  for (int mt = 0; mt < 2; ++mt) {
    const int row = rbase + mt * 16 + l15;
    if (row < N_NODES) {
      const float* xr   = X  + (size_t)row * DD + lg * 4;
      float*       orow = Xp + (size_t)row * DD + lg * 4;
#pragma unroll
      for (int nt = 0; nt < 8; ++nt) {
        f32x4 x = *(const f32x4*)(xr + nt * 16);
        f32x4 v = acc[mt][nt] + x;
        f32x4 r;
        r[0] = v[0] > 0.f ? v[0] : 0.f;
        r[1] = v[1] > 0.f ? v[1] : 0.f;
        r[2] = v[2] > 0.f ? v[2] : 0.f;
        r[3] = v[3] > 0.f ? v[3] : 0.f;
        *(f32x4*)(orow + nt * 16) = r;
      }
    }
  }
}

extern "C" void kernel_launch(void* const* d_in, const int* in_sizes, int n_in,
                              void* d_out, int out_size, void* d_ws, size_t ws_size,
                              hipStream_t stream) {
  const float* X  = (const float*)d_in[0];
  const float* Y  = (const float*)d_in[1];
  const float* W  = (const float*)d_in[2];
  const int*   EI = (const int*)d_in[3];

  float* Xp = (float*)d_out;
  float* Yp = Xp + (size_t)N_NODES * DD;   // outputs concatenated: X' then Y'

  int* w      = (int*)d_ws;
  int* count  = w;                 // 10000
  int* rowptr = w + 10000;         // 10001
  int* cursor = w + 20001;         // 10000
  int* col    = w + 30001;         // 640000
  int* nid    = w + 670001;        // 640000
  float* segY = (float*)(w + 1310016);  // 10000*128 fp32 = 5.12 MB (aligned)

  k_zero<<<(N_NODES * DD + 255) / 256, 256, 0, stream>>>(count, segY);
  k_hist<<<N_EDGES / 256, 256, 0, stream>>>(EI, count);
  k_scan<<<1, 1024, 0, stream>>>(count, rowptr, cursor);
  k_fill<<<N_EDGES / 256, 256, 0, stream>>>(EI, cursor, col, nid);
  k_mega<<<N_EDGES / 256, 256, 0, stream>>>(Y, W, col, nid, Yp, segY);
  k_small<<<(N_NODES + 127) / 128, 256, 0, stream>>>(segY, W, X, Xp);
}

// Round 14
// 353.151 us; speedup vs baseline: 1.0281x; 1.0281x over previous
//
#include <hip/hip_runtime.h>

#define N_NODES 10000
#define N_EDGES 640000
#define DD 128

typedef __attribute__((ext_vector_type(8))) short short8;
typedef __attribute__((ext_vector_type(8))) float f32x8;
typedef __attribute__((ext_vector_type(4))) float f32x4;
typedef __attribute__((ext_vector_type(2))) float f32x2;

// pack two fp32 -> (bf16(hi)<<16)|bf16(lo), truncating: one v_perm_b32
__device__ __forceinline__ unsigned pack_bf2(float lo, float hi) {
  return __builtin_amdgcn_perm(__float_as_uint(hi), __float_as_uint(lo), 0x07060302u);
}

// Stage W (128x128 fp32 row-major) into LDS as bf16 with per-row XOR swizzle
// on 16B chunks (256-thread): chunk c of row j at slot (j*16)|(c^(j&7)).
__device__ __forceinline__ void stage_w256(const float* __restrict__ W,
                                           short8* lwr) {
  const int tid = threadIdx.x;
#pragma unroll
  for (int t = 0; t < 8; ++t) {
    int s = t * 256 + tid;                          // chunk id 0..2047
    f32x8 v = *(const f32x8*)(W + (size_t)s * 8);   // coalesced 32B cached
    short8 av;
    unsigned* au = (unsigned*)&av;
    au[0] = pack_bf2(v[0], v[1]);
    au[1] = pack_bf2(v[2], v[3]);
    au[2] = pack_bf2(v[4], v[5]);
    au[3] = pack_bf2(v[6], v[7]);
    int j = s >> 4;
    int c = s & 15;
    lwr[(j << 4) | (c ^ (j & 7))] = av;
  }
  __syncthreads();
}

__device__ __forceinline__ void pack_a(const f32x4* raw, short8* a) {
#pragma unroll
  for (int kk = 0; kk < 4; ++kk) {
    f32x4 v0 = raw[kk * 2];
    f32x4 v1 = raw[kk * 2 + 1];
    short8 av;
    unsigned* au = (unsigned*)&av;
    au[0] = pack_bf2(v0[0], v0[1]);
    au[1] = pack_bf2(v0[2], v0[3]);
    au[2] = pack_bf2(v1[0], v1[1]);
    au[3] = pack_bf2(v1[2], v1[3]);
    a[kk] = av;
  }
}

__device__ __forceinline__ void mfma_store(const short8* a, const short8* lwr,
                                           float* __restrict__ Yp,
                                           int row, int l15, int lg) {
  f32x4 acc[8];
#pragma unroll
  for (int nt = 0; nt < 8; ++nt)
    acc[nt] = (f32x4){0.f, 0.f, 0.f, 0.f};
#pragma unroll
  for (int nt = 0; nt < 8; ++nt) {
    const int j = nt * 16 + l15;                    // W row (= output col blk)
#pragma unroll
    for (int kk = 0; kk < 4; ++kk) {
      const int kc = kk * 4 + lg;
      short8 b = lwr[(j << 4) | (kc ^ (j & 7))];
      acc[nt] = __builtin_amdgcn_mfma_f32_16x16x32_bf16(b, a[kk], acc[nt], 0, 0, 0);
    }
  }
  float* orow = Yp + (size_t)row * DD + lg * 4;
#pragma unroll
  for (int nt = 0; nt < 8; ++nt)
    __builtin_nontemporal_store(acc[nt], (f32x4*)(orow + nt * 16));
}

// Two CONSECUTIVE 64-row chunks (c0, c0+1) with register prefetch: chunk 1's
// loads issue before chunk 0's MFMA, flying under it. Contiguous pairs keep
// the global read front compact (R11's stride walk destroyed locality).
__device__ __forceinline__ void gemm_chunk2(const float* __restrict__ Y,
                                            float* __restrict__ Yp,
                                            const short8* lwr, int c0) {
  const int wid  = threadIdx.x >> 6;
  const int lane = threadIdx.x & 63;
  const int l15  = lane & 15;
  const int lg   = lane >> 4;
  const int koff = lg * 8;
  const int row0 = c0 * 64 + wid * 16 + l15;

  f32x4 raw[8];
  const float* yr0 = Y + (size_t)row0 * DD + koff;
#pragma unroll
  for (int kk = 0; kk < 4; ++kk) {
    raw[kk * 2]     = *(const f32x4*)(yr0 + kk * 32);
    raw[kk * 2 + 1] = *(const f32x4*)(yr0 + kk * 32 + 4);
  }

  short8 a[4];
  pack_a(raw, a);                                   // waits chunk0 loads

  const float* yr1 = Y + (size_t)(row0 + 64) * DD + koff;
#pragma unroll
  for (int kk = 0; kk < 4; ++kk) {                  // prefetch chunk1
    raw[kk * 2]     = *(const f32x4*)(yr1 + kk * 32);
    raw[kk * 2 + 1] = *(const f32x4*)(yr1 + kk * 32 + 4);
  }

  mfma_store(a, lwr, Yp, row0, l15, lg);            // chunk0 under chunk1 loads

  pack_a(raw, a);                                   // waits chunk1 loads
  mfma_store(a, lwr, Yp, row0 + 64, l15, lg);
}

// ---------------------------------------------------------------------------
// k_zero: zero count histogram (and nothing else; segY is gather-written)
// ---------------------------------------------------------------------------
__global__ __launch_bounds__(256) void k_zero(int* __restrict__ count) {
  const int i = blockIdx.x * 256 + threadIdx.x;
  if (i < N_NODES) count[i] = 0;
}

// ---------------------------------------------------------------------------
// k_hist_gemm: 1250 blocks. Each: histogram 512 edges + gemm chunks
// {2b, 2b+1} (chunks 0..2499). Hist atomics hide under the gemm stream.
// ---------------------------------------------------------------------------
__global__ __launch_bounds__(256, 2) void k_hist_gemm(
    const int* __restrict__ EI, int* __restrict__ count,
    const float* __restrict__ Y, const float* __restrict__ W,
    float* __restrict__ Yp) {
  __shared__ short8 lwr[2048];
  const int e = blockIdx.x * 512 + threadIdx.x;
  atomicAdd(&count[EI[2 * e]], 1);
  atomicAdd(&count[EI[2 * (e + 256)]], 1);
  stage_w256(W, lwr);
  gemm_chunk2(Y, Yp, lwr, blockIdx.x * 2);
}

// ---------------------------------------------------------------------------
// k_scan: exclusive prefix sum of counts -> rowptr, cursor
// ---------------------------------------------------------------------------
__global__ __launch_bounds__(1024) void k_scan(const int* __restrict__ count,
                                               int* __restrict__ rowptr,
                                               int* __restrict__ cursor) {
  __shared__ int part[1024];
  const int tid = threadIdx.x;
  const int base = tid * 10;
  int local[10];
  int s = 0;
#pragma unroll
  for (int i = 0; i < 10; ++i) {
    const int idx = base + i;
    const int v = (idx < N_NODES) ? count[idx] : 0;
    local[i] = s;
    s += v;
  }
  part[tid] = s;
  __syncthreads();
  for (int off = 1; off < 1024; off <<= 1) {
    int v = 0;
    if (tid >= off) v = part[tid - off];
    __syncthreads();
    if (tid >= off) part[tid] += v;
    __syncthreads();
  }
  const int excl = (tid > 0) ? part[tid - 1] : 0;
#pragma unroll
  for (int i = 0; i < 10; ++i) {
    const int idx = base + i;
    if (idx < N_NODES) {
      const int r = excl + local[i];
      rowptr[idx] = r;
      cursor[idx] = r;
    }
  }
  if (tid == 1023) rowptr[N_NODES] = part[1023];
}

// ---------------------------------------------------------------------------
// k_fill_gemm: 1250 blocks. Each: CSR-fill 512 edges + gemm chunks
// {2500+2b, 2500+2b+1} (chunks 2500..4999).
// ---------------------------------------------------------------------------
__global__ __launch_bounds__(256, 2) void k_fill_gemm(
    const int* __restrict__ EI, int* __restrict__ cursor,
    int* __restrict__ col,
    const float* __restrict__ Y, const float* __restrict__ W,
    float* __restrict__ Yp) {
  __shared__ short8 lwr[2048];
  const int e = blockIdx.x * 512 + threadIdx.x;
  {
    const int s = EI[2 * e];
    const int pos = atomicAdd(&cursor[s], 1);
    col[pos] = e;
  }
  {
    const int e2 = e + 256;
    const int s = EI[2 * e2];
    const int pos = atomicAdd(&cursor[s], 1);
    col[pos] = e2;
  }
  stage_w256(W, lwr);
  gemm_chunk2(Y, Yp, lwr, 2500 + blockIdx.x * 2);
}

// ---------------------------------------------------------------------------
// k_main: 5000 blocks, role = bid % 2.
//   role 0 (2500 blocks): gather segY[n] = sum_{e in CSR[n]} Y[e]  (wave/node)
//   role 1 (2500 blocks): gemm chunk pair {5000+2g, +1}  (chunks 5000..9999)
// 1:1 block mix = 1:2 work mix (proven R9/R12 ratio), co-resident per CU.
// ---------------------------------------------------------------------------
__global__ __launch_bounds__(256, 2) void k_main(
    const float* __restrict__ Y,
    const float* __restrict__ W,
    const int* __restrict__ rowptr,
    const int* __restrict__ col,
    float* __restrict__ Yp,
    float* __restrict__ segY) {
  __shared__ short8 lwr[2048];
  const int role = blockIdx.x % 2;
  const int grp  = blockIdx.x / 2;
  const int wid  = threadIdx.x >> 6;
  const int lane = threadIdx.x & 63;

  if (role == 0) {
    // ---------------- gather path ----------------
    const int node = grp * 4 + wid;                // 2500*4 = 10000 exactly
    const size_t co = 2 * (size_t)lane;
    const int b  = rowptr[node];
    const int en = rowptr[node + 1];
    f32x2 acc = (f32x2){0.f, 0.f};
    int i = b;
    for (; i + 16 <= en; i += 16) {
      f32x2 v0 = *(const f32x2*)(Y + (size_t)col[i]      * DD + co);
      f32x2 v1 = *(const f32x2*)(Y + (size_t)col[i + 1]  * DD + co);
      f32x2 v2 = *(const f32x2*)(Y + (size_t)col[i + 2]  * DD + co);
      f32x2 v3 = *(const f32x2*)(Y + (size_t)col[i + 3]  * DD + co);
      f32x2 v4 = *(const f32x2*)(Y + (size_t)col[i + 4]  * DD + co);
      f32x2 v5 = *(const f32x2*)(Y + (size_t)col[i + 5]  * DD + co);
      f32x2 v6 = *(const f32x2*)(Y + (size_t)col[i + 6]  * DD + co);
      f32x2 v7 = *(const f32x2*)(Y + (size_t)col[i + 7]  * DD + co);
      f32x2 v8 = *(const f32x2*)(Y + (size_t)col[i + 8]  * DD + co);
      f32x2 v9 = *(const f32x2*)(Y + (size_t)col[i + 9]  * DD + co);
      f32x2 va = *(const f32x2*)(Y + (size_t)col[i + 10] * DD + co);
      f32x2 vb = *(const f32x2*)(Y + (size_t)col[i + 11] * DD + co);
      f32x2 vc = *(const f32x2*)(Y + (size_t)col[i + 12] * DD + co);
      f32x2 vd = *(const f32x2*)(Y + (size_t)col[i + 13] * DD + co);
      f32x2 ve = *(const f32x2*)(Y + (size_t)col[i + 14] * DD + co);
      f32x2 vf = *(const f32x2*)(Y + (size_t)col[i + 15] * DD + co);
      acc += v0; acc += v1; acc += v2; acc += v3;
      acc += v4; acc += v5; acc += v6; acc += v7;
      acc += v8; acc += v9; acc += va; acc += vb;
      acc += vc; acc += vd; acc += ve; acc += vf;
    }
    for (; i < en; ++i) {
      acc += *(const f32x2*)(Y + (size_t)col[i] * DD + co);
    }
    *(f32x2*)(segY + (size_t)node * DD + co) = acc;
    return;
  }

  // ---------------- gemm path: chunk pair ----------------
  stage_w256(W, lwr);
  gemm_chunk2(Y, Yp, lwr, 5000 + grp * 2);
}

// ---------------------------------------------------------------------------
// Small GEMM + epilogue: X' = relu(X + segY @ W^T)  (10000x128, fp32 I/O)
// ---------------------------------------------------------------------------
__global__ __launch_bounds__(256, 2) void k_small(
    const float* __restrict__ segY,
    const float* __restrict__ W,
    const float* __restrict__ X,
    float* __restrict__ Xp) {
  __shared__ short8 lwr[2048];
  stage_w256(W, lwr);
  const int wid  = threadIdx.x >> 6;
  const int lane = threadIdx.x & 63;
  const int l15  = lane & 15;
  const int lg   = lane >> 4;
  const int koff = lg * 8;
  const int rbase = blockIdx.x * 128 + wid * 32;

  short8 a[2][4];
#pragma unroll
  for (int mt = 0; mt < 2; ++mt) {
    int row = rbase + mt * 16 + l15;
    if (row > N_NODES - 1) row = N_NODES - 1;   // clamp (stores guarded)
    const float* sr = segY + (size_t)row * DD + koff;
#pragma unroll
    for (int kk = 0; kk < 4; ++kk) {
      f32x8 v = *(const f32x8*)(sr + kk * 32);
      short8 av;
      unsigned* au = (unsigned*)&av;
      au[0] = pack_bf2(v[0], v[1]);
      au[1] = pack_bf2(v[2], v[3]);
      au[2] = pack_bf2(v[4], v[5]);
      au[3] = pack_bf2(v[6], v[7]);
      a[mt][kk] = av;
    }
  }

  f32x4 acc[2][8];
#pragma unroll
  for (int mt = 0; mt < 2; ++mt)
#pragma unroll
    for (int nt = 0; nt < 8; ++nt)
      acc[mt][nt] = (f32x4){0.f, 0.f, 0.f, 0.f};

#pragma unroll
  for (int nt = 0; nt < 8; ++nt) {
    const int j = nt * 16 + l15;
#pragma unroll
    for (int kk = 0; kk < 4; ++kk) {
      const int kc = kk * 4 + lg;
      short8 b = lwr[(j << 4) | (kc ^ (j & 7))];
      acc[0][nt] = __builtin_amdgcn_mfma_f32_16x16x32_bf16(b, a[0][kk], acc[0][nt], 0, 0, 0);
      acc[1][nt] = __builtin_amdgcn_mfma_f32_16x16x32_bf16(b, a[1][kk], acc[1][nt], 0, 0, 0);
    }
  }

#pragma unroll
  for (int mt = 0; mt < 2; ++mt) {
    const int row = rbase + mt * 16 + l15;
    if (row < N_NODES) {
      const float* xr   = X  + (size_t)row * DD + lg * 4;
      float*       orow = Xp + (size_t)row * DD + lg * 4;
#pragma unroll
      for (int nt = 0; nt < 8; ++nt) {
        f32x4 x = *(const f32x4*)(xr + nt * 16);
        f32x4 v = acc[mt][nt] + x;
        f32x4 r;
        r[0] = v[0] > 0.f ? v[0] : 0.f;
        r[1] = v[1] > 0.f ? v[1] : 0.f;
        r[2] = v[2] > 0.f ? v[2] : 0.f;
        r[3] = v[3] > 0.f ? v[3] : 0.f;
        *(f32x4*)(orow + nt * 16) = r;
      }
    }
  }
}

extern "C" void kernel_launch(void* const* d_in, const int* in_sizes, int n_in,
                              void* d_out, int out_size, void* d_ws, size_t ws_size,
                              hipStream_t stream) {
  const float* X  = (const float*)d_in[0];
  const float* Y  = (const float*)d_in[1];
  const float* W  = (const float*)d_in[2];
  const int*   EI = (const int*)d_in[3];

  float* Xp = (float*)d_out;
  float* Yp = Xp + (size_t)N_NODES * DD;   // outputs concatenated: X' then Y'

  int* w      = (int*)d_ws;
  int* count  = w;                // 10000
  int* rowptr = w + 10000;        // 10001
  int* cursor = w + 20001;        // 10000
  int* col    = w + 30001;        // 640000
  float* segY = (float*)(w + 670001 + 15);  // 10000*128 fp32 = 5.12 MB

  k_zero<<<(N_NODES + 255) / 256, 256, 0, stream>>>(count);
  k_hist_gemm<<<1250, 256, 0, stream>>>(EI, count, Y, W, Yp);
  k_scan<<<1, 1024, 0, stream>>>(count, rowptr, cursor);
  k_fill_gemm<<<1250, 256, 0, stream>>>(EI, cursor, col, Y, W, Yp);
  k_main<<<5000, 256, 0, stream>>>(Y, W, rowptr, col, Yp, segY);
  k_small<<<(N_NODES + 127) / 128, 256, 0, stream>>>(segY, W, X, Xp);
}

// Round 15
// 274.984 us; speedup vs baseline: 1.3204x; 1.2843x over previous
//
#include <hip/hip_runtime.h>

#define N_NODES 10000
#define N_EDGES 640000
#define DD 128
// CSR-build kernels each carry 2500 gemm chunks (64 rows each); k_main
// carries the remaining 5000 chunks + the gather (role = bid%3, R9 mix).
#define MAIN_BLOCKS 7500

typedef __attribute__((ext_vector_type(8))) short short8;
typedef __attribute__((ext_vector_type(8))) float f32x8;
typedef __attribute__((ext_vector_type(4))) float f32x4;
typedef __attribute__((ext_vector_type(2))) float f32x2;

// pack two fp32 -> (bf16(hi)<<16)|bf16(lo), truncating: one v_perm_b32
__device__ __forceinline__ unsigned pack_bf2(float lo, float hi) {
  return __builtin_amdgcn_perm(__float_as_uint(hi), __float_as_uint(lo), 0x07060302u);
}

// Stage W (128x128 fp32 row-major) into LDS as bf16 with per-row XOR swizzle
// on 16B chunks (256-thread): chunk c of row j at slot (j*16)|(c^(j&7)).
__device__ __forceinline__ void stage_w256(const float* __restrict__ W,
                                           short8* lwr) {
  const int tid = threadIdx.x;
#pragma unroll
  for (int t = 0; t < 8; ++t) {
    int s = t * 256 + tid;                          // chunk id 0..2047
    f32x8 v = *(const f32x8*)(W + (size_t)s * 8);   // coalesced 32B cached
    short8 av;
    unsigned* au = (unsigned*)&av;
    au[0] = pack_bf2(v[0], v[1]);
    au[1] = pack_bf2(v[2], v[3]);
    au[2] = pack_bf2(v[4], v[5]);
    au[3] = pack_bf2(v[6], v[7]);
    int j = s >> 4;
    int c = s & 15;
    lwr[(j << 4) | (c ^ (j & 7))] = av;
  }
  __syncthreads();
}

// One 64-row gemm chunk (R10 structure): wave per 16 rows, swapped-operand
// MFMA -> each lane's f32x4 acc = 4 consecutive Yp cols -> contiguous
// dwordx4 NT stores. chunk in [0, 10000). One-shot, low-VGPR (the proven
// optimum: pipelined variants R7/R11/R14 all lost via occupancy/locality).
__device__ __forceinline__ void gemm_chunk(const float* __restrict__ Y,
                                           float* __restrict__ Yp,
                                           const short8* lwr, int chunk) {
  const int wid  = threadIdx.x >> 6;
  const int lane = threadIdx.x & 63;
  const int l15  = lane & 15;
  const int lg   = lane >> 4;
  const int koff = lg * 8;
  const int row  = chunk * 64 + wid * 16 + l15;

  const float* yr = Y + (size_t)row * DD;
  short8 a[4];
#pragma unroll
  for (int kk = 0; kk < 4; ++kk) {
    f32x8 v = *(const f32x8*)(yr + kk * 32 + koff);
    short8 av;
    unsigned* au = (unsigned*)&av;
    au[0] = pack_bf2(v[0], v[1]);
    au[1] = pack_bf2(v[2], v[3]);
    au[2] = pack_bf2(v[4], v[5]);
    au[3] = pack_bf2(v[6], v[7]);
    a[kk] = av;
  }

  f32x4 acc[8];
#pragma unroll
  for (int nt = 0; nt < 8; ++nt)
    acc[nt] = (f32x4){0.f, 0.f, 0.f, 0.f};

#pragma unroll
  for (int nt = 0; nt < 8; ++nt) {
    const int j = nt * 16 + l15;                    // W row (= output col blk)
#pragma unroll
    for (int kk = 0; kk < 4; ++kk) {
      const int kc = kk * 4 + lg;
      short8 b = lwr[(j << 4) | (kc ^ (j & 7))];
      acc[nt] = __builtin_amdgcn_mfma_f32_16x16x32_bf16(b, a[kk], acc[nt], 0, 0, 0);
    }
  }

  float* orow = Yp + (size_t)row * DD + lg * 4;
#pragma unroll
  for (int nt = 0; nt < 8; ++nt)
    __builtin_nontemporal_store(acc[nt], (f32x4*)(orow + nt * 16));
}

// ---------------------------------------------------------------------------
// k_zero: init histogram
// ---------------------------------------------------------------------------
__global__ __launch_bounds__(256) void k_zero(int* __restrict__ count) {
  const int i = blockIdx.x * 256 + threadIdx.x;
  if (i < N_NODES) count[i] = 0;
}

// ---------------------------------------------------------------------------
// k_hist_gemm: 2500 blocks. Each: histogram 256 edges + gemm chunk bid
// (chunks 0..2499). The hist atomics/EI-read hide under the gemm stream.
// ---------------------------------------------------------------------------
__global__ __launch_bounds__(256, 2) void k_hist_gemm(
    const int* __restrict__ EI, int* __restrict__ count,
    const float* __restrict__ Y, const float* __restrict__ W,
    float* __restrict__ Yp) {
  __shared__ short8 lwr[2048];
  const int e = blockIdx.x * 256 + threadIdx.x;
  atomicAdd(&count[EI[2 * e]], 1);
  stage_w256(W, lwr);
  gemm_chunk(Y, Yp, lwr, blockIdx.x);
}

// ---------------------------------------------------------------------------
// k_scan: exclusive prefix sum of counts -> rowptr, cursor
// ---------------------------------------------------------------------------
__global__ __launch_bounds__(1024) void k_scan(const int* __restrict__ count,
                                               int* __restrict__ rowptr,
                                               int* __restrict__ cursor) {
  __shared__ int part[1024];
  const int tid = threadIdx.x;
  const int base = tid * 10;
  int local[10];
  int s = 0;
#pragma unroll
  for (int i = 0; i < 10; ++i) {
    const int idx = base + i;
    const int v = (idx < N_NODES) ? count[idx] : 0;
    local[i] = s;
    s += v;
  }
  part[tid] = s;
  __syncthreads();
  for (int off = 1; off < 1024; off <<= 1) {
    int v = 0;
    if (tid >= off) v = part[tid - off];
    __syncthreads();
    if (tid >= off) part[tid] += v;
    __syncthreads();
  }
  const int excl = (tid > 0) ? part[tid - 1] : 0;
#pragma unroll
  for (int i = 0; i < 10; ++i) {
    const int idx = base + i;
    if (idx < N_NODES) {
      const int r = excl + local[i];
      rowptr[idx] = r;
      cursor[idx] = r;
    }
  }
  if (tid == 1023) rowptr[N_NODES] = part[1023];
}

// ---------------------------------------------------------------------------
// k_fill_gemm: 2500 blocks. Each: CSR-fill 256 edges + gemm chunk 2500+bid.
// ---------------------------------------------------------------------------
__global__ __launch_bounds__(256, 2) void k_fill_gemm(
    const int* __restrict__ EI, int* __restrict__ cursor,
    int* __restrict__ col,
    const float* __restrict__ Y, const float* __restrict__ W,
    float* __restrict__ Yp) {
  __shared__ short8 lwr[2048];
  const int e = blockIdx.x * 256 + threadIdx.x;
  const int s = EI[2 * e];
  const int pos = atomicAdd(&cursor[s], 1);
  col[pos] = e;
  stage_w256(W, lwr);
  gemm_chunk(Y, Yp, lwr, 2500 + blockIdx.x);
}

// ---------------------------------------------------------------------------
// k_main: role = bid % 3.
//   role 0 (2500 blocks): gather segY[n] = sum_{e in CSR[n]} Y[e]  (wave/node)
//   roles 1,2 (5000 blocks): gemm chunks 5000..9999
// ---------------------------------------------------------------------------
__global__ __launch_bounds__(256, 2) void k_main(
    const float* __restrict__ Y,
    const float* __restrict__ W,
    const int* __restrict__ rowptr,
    const int* __restrict__ col,
    float* __restrict__ Yp,
    float* __restrict__ segY) {
  __shared__ short8 lwr[2048];
  const int role = blockIdx.x % 3;
  const int grp  = blockIdx.x / 3;
  const int wid  = threadIdx.x >> 6;
  const int lane = threadIdx.x & 63;

  if (role == 0) {
    // ---------------- gather path ----------------
    const int node = grp * 4 + wid;                // 2500*4 = 10000 exactly
    const size_t co = 2 * (size_t)lane;
    const int b  = rowptr[node];
    const int en = rowptr[node + 1];
    f32x2 acc = (f32x2){0.f, 0.f};
    int i = b;
    for (; i + 16 <= en; i += 16) {
      f32x2 v0 = *(const f32x2*)(Y + (size_t)col[i]      * DD + co);
      f32x2 v1 = *(const f32x2*)(Y + (size_t)col[i + 1]  * DD + co);
      f32x2 v2 = *(const f32x2*)(Y + (size_t)col[i + 2]  * DD + co);
      f32x2 v3 = *(const f32x2*)(Y + (size_t)col[i + 3]  * DD + co);
      f32x2 v4 = *(const f32x2*)(Y + (size_t)col[i + 4]  * DD + co);
      f32x2 v5 = *(const f32x2*)(Y + (size_t)col[i + 5]  * DD + co);
      f32x2 v6 = *(const f32x2*)(Y + (size_t)col[i + 6]  * DD + co);
      f32x2 v7 = *(const f32x2*)(Y + (size_t)col[i + 7]  * DD + co);
      f32x2 v8 = *(const f32x2*)(Y + (size_t)col[i + 8]  * DD + co);
      f32x2 v9 = *(const f32x2*)(Y + (size_t)col[i + 9]  * DD + co);
      f32x2 va = *(const f32x2*)(Y + (size_t)col[i + 10] * DD + co);
      f32x2 vb = *(const f32x2*)(Y + (size_t)col[i + 11] * DD + co);
      f32x2 vc = *(const f32x2*)(Y + (size_t)col[i + 12] * DD + co);
      f32x2 vd = *(const f32x2*)(Y + (size_t)col[i + 13] * DD + co);
      f32x2 ve = *(const f32x2*)(Y + (size_t)col[i + 14] * DD + co);
      f32x2 vf = *(const f32x2*)(Y + (size_t)col[i + 15] * DD + co);
      acc += v0; acc += v1; acc += v2; acc += v3;
      acc += v4; acc += v5; acc += v6; acc += v7;
      acc += v8; acc += v9; acc += va; acc += vb;
      acc += vc; acc += vd; acc += ve; acc += vf;
    }
    for (; i < en; ++i) {
      acc += *(const f32x2*)(Y + (size_t)col[i] * DD + co);
    }
    *(f32x2*)(segY + (size_t)node * DD + co) = acc;
    return;
  }

  // ---------------- gemm path: chunks 5000..9999 ----------------
  stage_w256(W, lwr);
  gemm_chunk(Y, Yp, lwr, 5000 + grp * 2 + (role - 1));
}

// ---------------------------------------------------------------------------
// Small GEMM + epilogue: X' = relu(X + segY @ W^T)  (10000x128, fp32 I/O)
// ---------------------------------------------------------------------------
__global__ __launch_bounds__(256, 2) void k_small(
    const float* __restrict__ segY,
    const float* __restrict__ W,
    const float* __restrict__ X,
    float* __restrict__ Xp) {
  __shared__ short8 lwr[2048];
  stage_w256(W, lwr);
  const int wid  = threadIdx.x >> 6;
  const int lane = threadIdx.x & 63;
  const int l15  = lane & 15;
  const int lg   = lane >> 4;
  const int koff = lg * 8;
  const int rbase = blockIdx.x * 128 + wid * 32;

  short8 a[2][4];
#pragma unroll
  for (int mt = 0; mt < 2; ++mt) {
    int row = rbase + mt * 16 + l15;
    if (row > N_NODES - 1) row = N_NODES - 1;   // clamp (stores guarded)
    const float* sr = segY + (size_t)row * DD + koff;
#pragma unroll
    for (int kk = 0; kk < 4; ++kk) {
      f32x8 v = *(const f32x8*)(sr + kk * 32);
      short8 av;
      unsigned* au = (unsigned*)&av;
      au[0] = pack_bf2(v[0], v[1]);
      au[1] = pack_bf2(v[2], v[3]);
      au[2] = pack_bf2(v[4], v[5]);
      au[3] = pack_bf2(v[6], v[7]);
      a[mt][kk] = av;
    }
  }

  f32x4 acc[2][8];
#pragma unroll
  for (int mt = 0; mt < 2; ++mt)
#pragma unroll
    for (int nt = 0; nt < 8; ++nt)
      acc[mt][nt] = (f32x4){0.f, 0.f, 0.f, 0.f};

#pragma unroll
  for (int nt = 0; nt < 8; ++nt) {
    const int j = nt * 16 + l15;
#pragma unroll
    for (int kk = 0; kk < 4; ++kk) {
      const int kc = kk * 4 + lg;
      short8 b = lwr[(j << 4) | (kc ^ (j & 7))];
      acc[0][nt] = __builtin_amdgcn_mfma_f32_16x16x32_bf16(b, a[0][kk], acc[0][nt], 0, 0, 0);
      acc[1][nt] = __builtin_amdgcn_mfma_f32_16x16x32_bf16(b, a[1][kk], acc[1][nt], 0, 0, 0);
    }
  }

#pragma unroll
  for (int mt = 0; mt < 2; ++mt) {
    const int row = rbase + mt * 16 + l15;
    if (row < N_NODES) {
      const float* xr   = X  + (size_t)row * DD + lg * 4;
      float*       orow = Xp + (size_t)row * DD + lg * 4;
#pragma unroll
      for (int nt = 0; nt < 8; ++nt) {
        f32x4 x = *(const f32x4*)(xr + nt * 16);
        f32x4 v = acc[mt][nt] + x;
        f32x4 r;
        r[0] = v[0] > 0.f ? v[0] : 0.f;
        r[1] = v[1] > 0.f ? v[1] : 0.f;
        r[2] = v[2] > 0.f ? v[2] : 0.f;
        r[3] = v[3] > 0.f ? v[3] : 0.f;
        *(f32x4*)(orow + nt * 16) = r;
      }
    }
  }
}

extern "C" void kernel_launch(void* const* d_in, const int* in_sizes, int n_in,
                              void* d_out, int out_size, void* d_ws, size_t ws_size,
                              hipStream_t stream) {
  const float* X  = (const float*)d_in[0];
  const float* Y  = (const float*)d_in[1];
  const float* W  = (const float*)d_in[2];
  const int*   EI = (const int*)d_in[3];

  float* Xp = (float*)d_out;
  float* Yp = Xp + (size_t)N_NODES * DD;   // outputs concatenated: X' then Y'

  int* w      = (int*)d_ws;
  int* count  = w;                // 10000
  int* rowptr = w + 10000;        // 10001
  int* cursor = w + 20001;        // 10000
  int* col    = w + 30001;        // 640000
  float* segY = (float*)(w + 670001 + 15);  // 10000*128 fp32 = 5.12 MB

  k_zero<<<(N_NODES + 255) / 256, 256, 0, stream>>>(count);
  k_hist_gemm<<<2500, 256, 0, stream>>>(EI, count, Y, W, Yp);
  k_scan<<<1, 1024, 0, stream>>>(count, rowptr, cursor);
  k_fill_gemm<<<2500, 256, 0, stream>>>(EI, cursor, col, Y, W, Yp);
  k_main<<<MAIN_BLOCKS, 256, 0, stream>>>(Y, W, rowptr, col, Yp, segY);
  k_small<<<(N_NODES + 127) / 128, 256, 0, stream>>>(segY, W, X, Xp);
}

// Round 16
// 263.018 us; speedup vs baseline: 1.3805x; 1.0455x over previous
//
#include <hip/hip_runtime.h>

#define N_NODES 10000
#define N_EDGES 640000
#define DD 128
// CSR-build kernels each carry 2500 gemm chunks (64 rows each); k_main
// carries the remaining 5000 chunks + the gather (role = bid%3, R9 mix).
#define MAIN_BLOCKS 7500

typedef __attribute__((ext_vector_type(8))) short short8;
typedef __attribute__((ext_vector_type(8))) float f32x8;
typedef __attribute__((ext_vector_type(4))) float f32x4;
typedef __attribute__((ext_vector_type(2))) float f32x2;

// pack two fp32 -> (bf16(hi)<<16)|bf16(lo), truncating: one v_perm_b32
__device__ __forceinline__ unsigned pack_bf2(float lo, float hi) {
  return __builtin_amdgcn_perm(__float_as_uint(hi), __float_as_uint(lo), 0x07060302u);
}

// Stage W (128x128 fp32 row-major) into LDS as bf16 with per-row XOR swizzle
// on 16B chunks (256-thread): chunk c of row j at slot (j*16)|(c^(j&7)).
__device__ __forceinline__ void stage_w256(const float* __restrict__ W,
                                           short8* lwr) {
  const int tid = threadIdx.x;
#pragma unroll
  for (int t = 0; t < 8; ++t) {
    int s = t * 256 + tid;                          // chunk id 0..2047
    f32x8 v = *(const f32x8*)(W + (size_t)s * 8);   // coalesced 32B cached
    short8 av;
    unsigned* au = (unsigned*)&av;
    au[0] = pack_bf2(v[0], v[1]);
    au[1] = pack_bf2(v[2], v[3]);
    au[2] = pack_bf2(v[4], v[5]);
    au[3] = pack_bf2(v[6], v[7]);
    int j = s >> 4;
    int c = s & 15;
    lwr[(j << 4) | (c ^ (j & 7))] = av;
  }
  __syncthreads();
}

// One 64-row gemm chunk (R10 structure): wave per 16 rows, swapped-operand
// MFMA -> each lane's f32x4 acc = 4 consecutive Yp cols -> contiguous
// dwordx4 NT stores. One-shot, low-VGPR (pipelined variants R7/R11/R14 all
// lost via occupancy/locality).
__device__ __forceinline__ void gemm_chunk(const float* __restrict__ Y,
                                           float* __restrict__ Yp,
                                           const short8* lwr, int chunk) {
  const int wid  = threadIdx.x >> 6;
  const int lane = threadIdx.x & 63;
  const int l15  = lane & 15;
  const int lg   = lane >> 4;
  const int koff = lg * 8;
  const int row  = chunk * 64 + wid * 16 + l15;

  const float* yr = Y + (size_t)row * DD;
  short8 a[4];
#pragma unroll
  for (int kk = 0; kk < 4; ++kk) {
    f32x8 v = *(const f32x8*)(yr + kk * 32 + koff);
    short8 av;
    unsigned* au = (unsigned*)&av;
    au[0] = pack_bf2(v[0], v[1]);
    au[1] = pack_bf2(v[2], v[3]);
    au[2] = pack_bf2(v[4], v[5]);
    au[3] = pack_bf2(v[6], v[7]);
    a[kk] = av;
  }

  f32x4 acc[8];
#pragma unroll
  for (int nt = 0; nt < 8; ++nt)
    acc[nt] = (f32x4){0.f, 0.f, 0.f, 0.f};

#pragma unroll
  for (int nt = 0; nt < 8; ++nt) {
    const int j = nt * 16 + l15;                    // W row (= output col blk)
#pragma unroll
    for (int kk = 0; kk < 4; ++kk) {
      const int kc = kk * 4 + lg;
      short8 b = lwr[(j << 4) | (kc ^ (j & 7))];
      acc[nt] = __builtin_amdgcn_mfma_f32_16x16x32_bf16(b, a[kk], acc[nt], 0, 0, 0);
    }
  }

  float* orow = Yp + (size_t)row * DD + lg * 4;
#pragma unroll
  for (int nt = 0; nt < 8; ++nt)
    __builtin_nontemporal_store(acc[nt], (f32x4*)(orow + nt * 16));
}

// ---------------------------------------------------------------------------
// k_zero: init histogram
// ---------------------------------------------------------------------------
__global__ __launch_bounds__(256) void k_zero(int* __restrict__ count) {
  const int i = blockIdx.x * 256 + threadIdx.x;
  if (i < N_NODES) count[i] = 0;
}

// ---------------------------------------------------------------------------
// k_hist_gemm: 2500 blocks. Each: histogram 256 edges + gemm chunk bid
// (chunks 0..2499). The hist atomics/EI-read hide under the gemm stream.
// ---------------------------------------------------------------------------
__global__ __launch_bounds__(256, 2) void k_hist_gemm(
    const int* __restrict__ EI, int* __restrict__ count,
    const float* __restrict__ Y, const float* __restrict__ W,
    float* __restrict__ Yp) {
  __shared__ short8 lwr[2048];
  const int e = blockIdx.x * 256 + threadIdx.x;
  atomicAdd(&count[EI[2 * e]], 1);
  stage_w256(W, lwr);
  gemm_chunk(Y, Yp, lwr, blockIdx.x);
}

// ---------------------------------------------------------------------------
// k_scan: exclusive prefix sum of counts -> rowptr, cursor
// ---------------------------------------------------------------------------
__global__ __launch_bounds__(1024) void k_scan(const int* __restrict__ count,
                                               int* __restrict__ rowptr,
                                               int* __restrict__ cursor) {
  __shared__ int part[1024];
  const int tid = threadIdx.x;
  const int base = tid * 10;
  int local[10];
  int s = 0;
#pragma unroll
  for (int i = 0; i < 10; ++i) {
    const int idx = base + i;
    const int v = (idx < N_NODES) ? count[idx] : 0;
    local[i] = s;
    s += v;
  }
  part[tid] = s;
  __syncthreads();
  for (int off = 1; off < 1024; off <<= 1) {
    int v = 0;
    if (tid >= off) v = part[tid - off];
    __syncthreads();
    if (tid >= off) part[tid] += v;
    __syncthreads();
  }
  const int excl = (tid > 0) ? part[tid - 1] : 0;
#pragma unroll
  for (int i = 0; i < 10; ++i) {
    const int idx = base + i;
    if (idx < N_NODES) {
      const int r = excl + local[i];
      rowptr[idx] = r;
      cursor[idx] = r;
    }
  }
  if (tid == 1023) rowptr[N_NODES] = part[1023];
}

// ---------------------------------------------------------------------------
// k_fill_gemm: 2500 blocks. Each: CSR-fill 256 edges + gemm chunk 2500+bid.
// ---------------------------------------------------------------------------
__global__ __launch_bounds__(256, 2) void k_fill_gemm(
    const int* __restrict__ EI, int* __restrict__ cursor,
    int* __restrict__ col,
    const float* __restrict__ Y, const float* __restrict__ W,
    float* __restrict__ Yp) {
  __shared__ short8 lwr[2048];
  const int e = blockIdx.x * 256 + threadIdx.x;
  const int s = EI[2 * e];
  const int pos = atomicAdd(&cursor[s], 1);
  col[pos] = e;
  stage_w256(W, lwr);
  gemm_chunk(Y, Yp, lwr, 2500 + blockIdx.x);
}

// ---------------------------------------------------------------------------
// k_main: role = bid % 3.
//   role 0 (2500 blocks): gather segY[n] = sum_{e in CSR[n]} Y[e] (wave/node)
//     DUAL-ROW f32x4 loads: lane = (h = l>>5, m = l&31); one instruction
//     fetches rows col[i+h] (16B/lane x 32 lanes = 512B row, 2 rows/instr)
//     -> half the L3 request count of the 8B/lane version at equal MLP.
//     Cross-half reduce via 4x shfl_xor(32), store by lower half.
//   roles 1,2 (5000 blocks): gemm chunks 5000..9999
// ---------------------------------------------------------------------------
__global__ __launch_bounds__(256, 2) void k_main(
    const float* __restrict__ Y,
    const float* __restrict__ W,
    const int* __restrict__ rowptr,
    const int* __restrict__ col,
    float* __restrict__ Yp,
    float* __restrict__ segY) {
  __shared__ short8 lwr[2048];
  const int role = blockIdx.x % 3;
  const int grp  = blockIdx.x / 3;
  const int wid  = threadIdx.x >> 6;
  const int lane = threadIdx.x & 63;

  if (role == 0) {
    // ---------------- gather path (dual-row f32x4) ----------------
    const int node = grp * 4 + wid;                // 2500*4 = 10000 exactly
    const int h = lane >> 5;                       // edge-pair half
    const int m = lane & 31;                       // 16B slot within row
    const size_t co = 4 * (size_t)m;
    const int b  = rowptr[node];
    const int en = rowptr[node + 1];

    f32x4 acc = (f32x4){0.f, 0.f, 0.f, 0.f};
    int i = b;
    for (; i + 16 <= en; i += 16) {
      f32x4 v0 = *(const f32x4*)(Y + (size_t)col[i      + h] * DD + co);
      f32x4 v1 = *(const f32x4*)(Y + (size_t)col[i + 2  + h] * DD + co);
      f32x4 v2 = *(const f32x4*)(Y + (size_t)col[i + 4  + h] * DD + co);
      f32x4 v3 = *(const f32x4*)(Y + (size_t)col[i + 6  + h] * DD + co);
      f32x4 v4 = *(const f32x4*)(Y + (size_t)col[i + 8  + h] * DD + co);
      f32x4 v5 = *(const f32x4*)(Y + (size_t)col[i + 10 + h] * DD + co);
      f32x4 v6 = *(const f32x4*)(Y + (size_t)col[i + 12 + h] * DD + co);
      f32x4 v7 = *(const f32x4*)(Y + (size_t)col[i + 14 + h] * DD + co);
      acc += v0; acc += v1; acc += v2; acc += v3;
      acc += v4; acc += v5; acc += v6; acc += v7;
    }
    for (; i < en; i += 2) {
      const int p = i + h;
      if (p < en)
        acc += *(const f32x4*)(Y + (size_t)col[p] * DD + co);
    }
    // cross-half reduction: lane l += lane l^32
    f32x4 other;
    other[0] = __shfl_xor(acc[0], 32, 64);
    other[1] = __shfl_xor(acc[1], 32, 64);
    other[2] = __shfl_xor(acc[2], 32, 64);
    other[3] = __shfl_xor(acc[3], 32, 64);
    acc += other;
    if (h == 0)
      *(f32x4*)(segY + (size_t)node * DD + co) = acc;
    return;
  }

  // ---------------- gemm path: chunks 5000..9999 ----------------
  stage_w256(W, lwr);
  gemm_chunk(Y, Yp, lwr, 5000 + grp * 2 + (role - 1));
}

// ---------------------------------------------------------------------------
// Small GEMM + epilogue: X' = relu(X + segY @ W^T)  (10000x128, fp32 I/O)
// ---------------------------------------------------------------------------
__global__ __launch_bounds__(256, 2) void k_small(
    const float* __restrict__ segY,
    const float* __restrict__ W,
    const float* __restrict__ X,
    float* __restrict__ Xp) {
  __shared__ short8 lwr[2048];
  stage_w256(W, lwr);
  const int wid  = threadIdx.x >> 6;
  const int lane = threadIdx.x & 63;
  const int l15  = lane & 15;
  const int lg   = lane >> 4;
  const int koff = lg * 8;
  const int rbase = blockIdx.x * 128 + wid * 32;

  short8 a[2][4];
#pragma unroll
  for (int mt = 0; mt < 2; ++mt) {
    int row = rbase + mt * 16 + l15;
    if (row > N_NODES - 1) row = N_NODES - 1;   // clamp (stores guarded)
    const float* sr = segY + (size_t)row * DD + koff;
#pragma unroll
    for (int kk = 0; kk < 4; ++kk) {
      f32x8 v = *(const f32x8*)(sr + kk * 32);
      short8 av;
      unsigned* au = (unsigned*)&av;
      au[0] = pack_bf2(v[0], v[1]);
      au[1] = pack_bf2(v[2], v[3]);
      au[2] = pack_bf2(v[4], v[5]);
      au[3] = pack_bf2(v[6], v[7]);
      a[mt][kk] = av;
    }
  }

  f32x4 acc[2][8];
#pragma unroll
  for (int mt = 0; mt < 2; ++mt)
#pragma unroll
    for (int nt = 0; nt < 8; ++nt)
      acc[mt][nt] = (f32x4){0.f, 0.f, 0.f, 0.f};

#pragma unroll
  for (int nt = 0; nt < 8; ++nt) {
    const int j = nt * 16 + l15;
#pragma unroll
    for (int kk = 0; kk < 4; ++kk) {
      const int kc = kk * 4 + lg;
      short8 b = lwr[(j << 4) | (kc ^ (j & 7))];
      acc[0][nt] = __builtin_amdgcn_mfma_f32_16x16x32_bf16(b, a[0][kk], acc[0][nt], 0, 0, 0);
      acc[1][nt] = __builtin_amdgcn_mfma_f32_16x16x32_bf16(b, a[1][kk], acc[1][nt], 0, 0, 0);
    }
  }

#pragma unroll
  for (int mt = 0; mt < 2; ++mt) {
    const int row = rbase + mt * 16 + l15;
    if (row < N_NODES) {
      const float* xr   = X  + (size_t)row * DD + lg * 4;
      float*       orow = Xp + (size_t)row * DD + lg * 4;
#pragma unroll
      for (int nt = 0; nt < 8; ++nt) {
        f32x4 x = *(const f32x4*)(xr + nt * 16);
        f32x4 v = acc[mt][nt] + x;
        f32x4 r;
        r[0] = v[0] > 0.f ? v[0] : 0.f;
        r[1] = v[1] > 0.f ? v[1] : 0.f;
        r[2] = v[2] > 0.f ? v[2] : 0.f;
        r[3] = v[3] > 0.f ? v[3] : 0.f;
        *(f32x4*)(orow + nt * 16) = r;
      }
    }
  }
}

extern "C" void kernel_launch(void* const* d_in, const int* in_sizes, int n_in,
                              void* d_out, int out_size, void* d_ws, size_t ws_size,
                              hipStream_t stream) {
  const float* X  = (const float*)d_in[0];
  const float* Y  = (const float*)d_in[1];
  const float* W  = (const float*)d_in[2];
  const int*   EI = (const int*)d_in[3];

  float* Xp = (float*)d_out;
  float* Yp = Xp + (size_t)N_NODES * DD;   // outputs concatenated: X' then Y'

  int* w      = (int*)d_ws;
  int* count  = w;                // 10000
  int* rowptr = w + 10000;        // 10001
  int* cursor = w + 20001;        // 10000
  int* col    = w + 30001;        // 640000
  float* segY = (float*)(w + 670001 + 15);  // 10000*128 fp32 = 5.12 MB

  k_zero<<<(N_NODES + 255) / 256, 256, 0, stream>>>(count);
  k_hist_gemm<<<2500, 256, 0, stream>>>(EI, count, Y, W, Yp);
  k_scan<<<1, 1024, 0, stream>>>(count, rowptr, cursor);
  k_fill_gemm<<<2500, 256, 0, stream>>>(EI, cursor, col, Y, W, Yp);
  k_main<<<MAIN_BLOCKS, 256, 0, stream>>>(Y, W, rowptr, col, Yp, segY);
  k_small<<<(N_NODES + 127) / 128, 256, 0, stream>>>(segY, W, X, Xp);
}